// Round 6
// baseline (998.311 us; speedup 1.0000x reference)
//
#include <hip/hip_runtime.h>
#include <hip/hip_bf16.h>

typedef __attribute__((ext_vector_type(4))) float f32x4;
typedef __attribute__((ext_vector_type(8))) short short8;

#define LTOK 64
#define CDIM 256

static __device__ __forceinline__ short f2bf(float f) {
    __hip_bfloat16 h = __float2bfloat16(f);
    union { __hip_bfloat16 b; short s; } u; u.b = h;
    return u.s;
}

// ---------------- prep kernels ----------------
__global__ void prep_weights(const float* __restrict__ qw, const float* __restrict__ pw,
                             short* __restrict__ wqs, short* __restrict__ wps) {
    int i = blockIdx.x * 256 + threadIdx.x;     // grid 768*256 = 196608
    if (i < 768 * 256) {
        int row = i >> 8, col = i & 255;
        int nt = row >> 4, lcr = row & 15;
        int kt = col >> 5, lg = (col >> 3) & 3, j = col & 7;
        wqs[(size_t)(((nt * 8 + kt) * 64) + lg * 16 + lcr) * 8 + j] = f2bf(qw[i]);
    }
    if (i < 256 * 256) {
        int row = i >> 8, col = i & 255;
        int gs = row >> 4, lcr = row & 15;          // global 16-col strip 0..15
        int h = col >> 5, lg = (col >> 3) & 3, j = col & 7;
        wps[(size_t)(((gs * 8 + h) * 64) + lg * 16 + lcr) * 8 + j] = f2bf(pw[i]);
    }
}

__global__ void prep_bias(const float* __restrict__ w1, const float* __restrict__ b1,
                          const float* __restrict__ w2, const float* __restrict__ b2,
                          const float* __restrict__ lsc, float* __restrict__ biasT,
                          float* __restrict__ scT) {
    int t = threadIdx.x;                         // 1 block, 128 threads
    if (t < 8) scT[t] = expf(fminf(lsc[t], logf(100.0f)));
    if (t < 127) {
        float delta = (float)(t - 63);
        float sg = (delta > 0.f) ? 1.f : ((delta < 0.f) ? -1.f : 0.f);
        float r = sg * log1pf(fabsf(delta));
        float acc[8];
        #pragma unroll
        for (int q = 0; q < 8; ++q) acc[q] = b2[q];
        for (int m = 0; m < 384; ++m) {
            float hid = fmaxf(fmaf(r, w1[m * 2 + 1], b1[m]), 0.f);
            #pragma unroll
            for (int q = 0; q < 8; ++q) acc[q] = fmaf(hid, w2[q * 384 + m], acc[q]);
        }
        #pragma unroll
        for (int q = 0; q < 8; ++q) biasT[q * 127 + t] = acc[q];
    }
}

// ---------------- main fused kernel ----------------
// R5 structure, LDS cut to 71680 B (< 74752 = R4's verified 2-block size):
// PBF halved — P is wave-private + consumed immediately, so a 512-short
// per-wave slice is written/read twice (k-cols 0..31 then 32..63).
// 512 threads (8 waves); fragment-linear LDS; 3 barriers per g;
// 2 blocks/CU -> 16 waves/CU.

__global__ void __launch_bounds__(512, 2)
fused_win_attn(const float* __restrict__ x,
               const float* __restrict__ qkv_b,
               const float* __restrict__ proj_b,
               const short* __restrict__ wqs,
               const short* __restrict__ wps,
               const float* __restrict__ biasT,
               const float* __restrict__ scT,
               float* __restrict__ out)
{
    __shared__ short XSF[16384];     // x frags [kt 0..7][rt 0..3]          32768 B
    __shared__ short U[4096];        // QGF [kt 0..1][rt 0..3] / AOF         8192 B
    __shared__ short KGF[4096];      // k frags                              8192 B
    __shared__ short VTF[4096];      // v^T frags                            8192 B
    __shared__ short PBF[4096];      // P, wave-private 512-short slices     8192 B
    __shared__ float NSQ[512];       // sumsq partials [s][row][nt]          2048 B
    __shared__ float BT[1024];       // bias table [h][rel+63]               4096 B
                                     // total 71680 B

    const int tid = threadIdx.x;
    const int w  = tid >> 6;
    const int l  = tid & 63;
    const int lg = l >> 4;
    const int lc = l & 15;
    const int blk = blockIdx.x;
    const int li4 = lg * 4;

    // ---- stage bias table ----
    #pragma unroll
    for (int u = 0; u < 2; ++u) {
        int idx = u * 512 + tid;
        if (idx < 8 * 127) {
            int h = idx / 127, d = idx - h * 127;
            BT[h * 128 + d] = biasT[idx];
        }
    }

    // ---- stage X once into fragment-linear LDS (conflict-free) ----
    {
        const float* xb = x + (size_t)blk * (LTOK * CDIM);
        #pragma unroll
        for (int q = 0; q < 4; ++q) {
            int f = q * 8 + w;                 // frag id: kt = f>>2, rt = f&3
            int kt = f >> 2, rt = f & 3;
            const float* src = xb + (size_t)(rt * 16 + lc) * CDIM + kt * 32 + lg * 8;
            f32x4 a = *(const f32x4*)(src);
            f32x4 b = *(const f32x4*)(src + 4);
            short8 t;
            t[0]=f2bf(a[0]); t[1]=f2bf(a[1]); t[2]=f2bf(a[2]); t[3]=f2bf(a[3]);
            t[4]=f2bf(b[0]); t[5]=f2bf(b[1]); t[6]=f2bf(b[2]); t[7]=f2bf(b[3]);
            *(short8*)(XSF + (size_t)(f * 64 + l) * 8) = t;
        }
    }

    f32x4 accP[4][2];                          // proj accumulators, persist
    #pragma unroll
    for (int a = 0; a < 4; ++a) { accP[a][0] = (f32x4){0,0,0,0}; accP[a][1] = (f32x4){0,0,0,0}; }
    const f32x4 fzero = {0.f, 0.f, 0.f, 0.f};

    const int mtb = (w >> 2) * 2;              // qkv m-tile base
    const int sb  = (w & 3) * 3;               // qkv strip base
    const int hh  = w >> 2;                    // attention: head within pair
    const int mw  = w & 3;                     // attention: q m-tile
    short* PW = PBF + w * 512;                 // wave-private P slice (one frag)

    __syncthreads();                           // B0: XSF + BT ready

    #pragma unroll 1
    for (int g = 0; g < 4; ++g) {
        // ======== qkv GEMM: 3 strips x 2 m-tiles per wave ========
        f32x4 acc[3][2];
        #pragma unroll
        for (int t = 0; t < 3; ++t) { acc[t][0] = fzero; acc[t][1] = fzero; }
        #pragma unroll
        for (int kt = 0; kt < 8; ++kt) {
            short8 Af0 = *(const short8*)(XSF + (size_t)((kt * 4 + mtb) * 64 + l) * 8);
            short8 Af1 = *(const short8*)(XSF + (size_t)((kt * 4 + mtb + 1) * 64 + l) * 8);
            #pragma unroll
            for (int tt = 0; tt < 3; ++tt) {
                const int strip = sb + tt;
                const int gnt = (strip >> 2) * 16 + g * 4 + (strip & 3);
                short8 Bf = *(const short8*)(wqs + (size_t)((gnt * 8 + kt) * 64 + l) * 8);
                acc[tt][0] = __builtin_amdgcn_mfma_f32_16x16x32_bf16(Af0, Bf, acc[tt][0], 0, 0, 0);
                acc[tt][1] = __builtin_amdgcn_mfma_f32_16x16x32_bf16(Af1, Bf, acc[tt][1], 0, 0, 0);
            }
        }
        // ---- epilogue: scatter into fragment-linear QGF/KGF/VTF + NSQ ----
        #pragma unroll
        for (int tt = 0; tt < 3; ++tt) {
            const int strip = sb + tt;
            const int s = strip >> 2, nt = strip & 3;
            const float bq = qkv_b[s * 256 + g * 64 + nt * 16 + lc];
            #pragma unroll
            for (int m = 0; m < 2; ++m) {
                const int mt = mtb + m;
                if (s == 2) {
                    #pragma unroll
                    for (int i = 0; i < 4; ++i) {
                        int tok = li4 + i;
                        VTF[(size_t)(((mt >> 1) * 4 + nt) * 64 + ((mt & 1) * 2 + (tok >> 3)) * 16 + lc) * 8 + (tok & 7)]
                            = f2bf(acc[tt][m][i] + bq);
                    }
                } else {
                    short* dst = s ? KGF : U;
                    const int ktc = nt >> 1;
                    const int lgc = (nt & 1) * 2 + (lc >> 3);
                    #pragma unroll
                    for (int i = 0; i < 4; ++i) {
                        float v = acc[tt][m][i] + bq;
                        dst[(size_t)((ktc * 4 + mt) * 64 + lgc * 16 + li4 + i) * 8 + (lc & 7)] = f2bf(v);
                        float t2 = v * v;
                        t2 += __shfl_xor(t2, 1);
                        t2 += __shfl_xor(t2, 2);
                        t2 += __shfl_xor(t2, 4);
                        t2 += __shfl_xor(t2, 8);
                        if (lc == 0) NSQ[s * 256 + (mt * 16 + li4 + i) * 4 + nt] = t2;
                    }
                }
            }
        }
        __syncthreads();                       // B1: QGF/KGF/VTF/NSQ ready

        // ======== attention (both heads concurrent across wave groups) ========
        {
            const int h = 2 * g + hh;
            const float sc = scT[h];
            short8 Aq = *(const short8*)(U + (size_t)((hh * 4 + mw) * 64 + l) * 8);
            f32x4 pacc[4];
            #pragma unroll
            for (int nt = 0; nt < 4; ++nt) {
                short8 Bk = *(const short8*)(KGF + (size_t)((hh * 4 + nt) * 64 + l) * 8);
                pacc[nt] = __builtin_amdgcn_mfma_f32_16x16x32_bf16(Aq, Bk, fzero, 0, 0, 0);
            }
            float invq[4], invk[4];
            #pragma unroll
            for (int i = 0; i < 4; ++i) {
                int r = mw * 16 + li4 + i;
                invq[i] = rsqrtf(NSQ[r * 4 + 2 * hh] + NSQ[r * 4 + 2 * hh + 1] + 1e-24f) * sc;
            }
            #pragma unroll
            for (int nt = 0; nt < 4; ++nt) {
                int rk = nt * 16 + lc;
                invk[nt] = rsqrtf(NSQ[256 + rk * 4 + 2 * hh] + NSQ[256 + rk * 4 + 2 * hh + 1] + 1e-24f);
            }
            float p[4][4];
            #pragma unroll
            for (int i = 0; i < 4; ++i) {
                int r = mw * 16 + li4 + i;
                #pragma unroll
                for (int nt = 0; nt < 4; ++nt)
                    p[i][nt] = pacc[nt][i] * invq[i] * invk[nt] + BT[h * 128 + r - (nt * 16 + lc) + 63];
            }
            // softmax over row (16-lane groups x 4 local); fold 1/sum into p
            #pragma unroll
            for (int i = 0; i < 4; ++i) {
                float m = fmaxf(fmaxf(p[i][0], p[i][1]), fmaxf(p[i][2], p[i][3]));
                m = fmaxf(m, __shfl_xor(m, 1));
                m = fmaxf(m, __shfl_xor(m, 2));
                m = fmaxf(m, __shfl_xor(m, 4));
                m = fmaxf(m, __shfl_xor(m, 8));
                float ssum = 0.f;
                #pragma unroll
                for (int nt = 0; nt < 4; ++nt) { p[i][nt] = __expf(p[i][nt] - m); ssum += p[i][nt]; }
                ssum += __shfl_xor(ssum, 1);
                ssum += __shfl_xor(ssum, 2);
                ssum += __shfl_xor(ssum, 4);
                ssum += __shfl_xor(ssum, 8);
                float rinv = 1.f / ssum;
                #pragma unroll
                for (int nt = 0; nt < 4; ++nt) p[i][nt] *= rinv;
            }
            // ---- P @ V: wave-private P frag reused twice (k-cols 0..31, 32..63) ----
            f32x4 oacc[2];
            oacc[0] = fzero; oacc[1] = fzero;
            #pragma unroll
            for (int kt = 0; kt < 2; ++kt) {
                #pragma unroll
                for (int i = 0; i < 4; ++i)
                    #pragma unroll
                    for (int nn = 0; nn < 2; ++nn)
                        PW[(size_t)(((nn * 2 + (lc >> 3)) * 16) + li4 + i) * 8 + (lc & 7)]
                            = f2bf(p[i][kt * 2 + nn]);
                short8 Ap = *(const short8*)(PW + (size_t)l * 8);
                #pragma unroll
                for (int nt2 = 0; nt2 < 2; ++nt2) {
                    short8 Bv = *(const short8*)(VTF + (size_t)((kt * 4 + hh * 2 + nt2) * 64 + l) * 8);
                    oacc[nt2] = __builtin_amdgcn_mfma_f32_16x16x32_bf16(Ap, Bv, oacc[nt2], 0, 0, 0);
                }
            }
            // AO into U slot (hh,mw) — same slot this wave read as Aq
            #pragma unroll
            for (int nt2 = 0; nt2 < 2; ++nt2)
                #pragma unroll
                for (int i = 0; i < 4; ++i)
                    U[(size_t)((hh * 4 + mw) * 64 + (nt2 * 2 + (lc >> 3)) * 16 + li4 + i) * 8 + (lc & 7)]
                        = f2bf(oacc[nt2][i]);
        }
        __syncthreads();                       // B2: AOF ready

        // ======== proj accumulate: wave w owns cols 32w..32w+31 ========
        #pragma unroll
        for (int hh2 = 0; hh2 < 2; ++hh2) {
            const int h2 = 2 * g + hh2;
            short8 Bp0 = *(const short8*)(wps + (size_t)(((w * 2 + 0) * 8 + h2) * 64 + l) * 8);
            short8 Bp1 = *(const short8*)(wps + (size_t)(((w * 2 + 1) * 8 + h2) * 64 + l) * 8);
            #pragma unroll
            for (int mt = 0; mt < 4; ++mt) {
                short8 Aa = *(const short8*)(U + (size_t)((hh2 * 4 + mt) * 64 + l) * 8);
                accP[mt][0] = __builtin_amdgcn_mfma_f32_16x16x32_bf16(Aa, Bp0, accP[mt][0], 0, 0, 0);
                accP[mt][1] = __builtin_amdgcn_mfma_f32_16x16x32_bf16(Aa, Bp1, accP[mt][1], 0, 0, 0);
            }
        }
        __syncthreads();                       // B3: proj done before next-g writes
    }

    // ---- epilogue: out = accP + proj_b ----
    {
        float* ob = out + (size_t)blk * (LTOK * CDIM);
        float pb0 = proj_b[w * 32 + lc];
        float pb1 = proj_b[w * 32 + 16 + lc];
        #pragma unroll
        for (int mt = 0; mt < 4; ++mt)
            #pragma unroll
            for (int i = 0; i < 4; ++i) {
                ob[(size_t)(mt * 16 + li4 + i) * 256 + w * 32 + lc]      = accP[mt][0][i] + pb0;
                ob[(size_t)(mt * 16 + li4 + i) * 256 + w * 32 + 16 + lc] = accP[mt][1][i] + pb1;
            }
    }
}

extern "C" void kernel_launch(void* const* d_in, const int* in_sizes, int n_in,
                              void* d_out, int out_size, void* d_ws, size_t ws_size,
                              hipStream_t stream) {
    const float* x     = (const float*)d_in[0];
    const float* qkvw  = (const float*)d_in[1];
    const float* qkvb  = (const float*)d_in[2];
    const float* projw = (const float*)d_in[3];
    const float* projb = (const float*)d_in[4];
    const float* lsc   = (const float*)d_in[5];
    const float* w1    = (const float*)d_in[6];
    const float* b1    = (const float*)d_in[7];
    const float* w2    = (const float*)d_in[8];
    const float* b2    = (const float*)d_in[9];
    float* out = (float*)d_out;

    // workspace layout
    short* wqs   = (short*)d_ws;                          // 393216 B
    short* wps   = (short*)((char*)d_ws + 393216);        // 131072 B
    float* biasT = (float*)((char*)d_ws + 524288);        // 4096 B
    float* scT   = (float*)((char*)d_ws + 528384);        // 32 B

    const int nwin = in_sizes[0] / (LTOK * CDIM);         // 4096

    prep_weights<<<768, 256, 0, stream>>>(qkvw, projw, wqs, wps);
    prep_bias<<<1, 128, 0, stream>>>(w1, b1, w2, b2, lsc, biasT, scT);
    fused_win_attn<<<nwin, 512, 0, stream>>>(x, qkvb, projb, wqs, wps, biasT, scT, out);
}

// Round 8
// 736.507 us; speedup vs baseline: 1.3555x; 1.3555x over previous
//
#include <hip/hip_runtime.h>
#include <hip/hip_bf16.h>

typedef __attribute__((ext_vector_type(4))) float f32x4;
typedef __attribute__((ext_vector_type(8))) short short8;
typedef __attribute__((ext_vector_type(4))) short short4_t;

#define LTOK 64
#define CDIM 256
#define FRS 576            // padded frag stride (shorts): 72 blocks x 8

static __device__ __forceinline__ short f2bf(float f) {
    __hip_bfloat16 h = __float2bfloat16(f);
    union { __hip_bfloat16 b; short s; } u; u.b = h;
    return u.s;
}
static __device__ __forceinline__ int KL(int l) { return l + (l >> 3); }

// ---------------- prep kernels ----------------
__global__ void prep_weights(const float* __restrict__ qw, const float* __restrict__ pw,
                             short* __restrict__ wqs, short* __restrict__ wps) {
    int i = blockIdx.x * 256 + threadIdx.x;     // grid 768*256 = 196608
    if (i < 768 * 256) {
        int row = i >> 8, col = i & 255;
        int nt = row >> 4, lcr = row & 15;
        int kt = col >> 5, lg = (col >> 3) & 3, j = col & 7;
        wqs[(size_t)(((nt * 8 + kt) * 64) + lg * 16 + lcr) * 8 + j] = f2bf(qw[i]);
    }
    if (i < 256 * 256) {
        int row = i >> 8, col = i & 255;
        int gs = row >> 4, lcr = row & 15;          // global 16-col strip 0..15
        int h = col >> 5, lg = (col >> 3) & 3, j = col & 7;
        wps[(size_t)(((gs * 8 + h) * 64) + lg * 16 + lcr) * 8 + j] = f2bf(pw[i]);
    }
}

__global__ void prep_bias(const float* __restrict__ w1, const float* __restrict__ b1,
                          const float* __restrict__ w2, const float* __restrict__ b2,
                          const float* __restrict__ lsc, float* __restrict__ biasT,
                          float* __restrict__ scT) {
    int t = threadIdx.x;                         // 1 block, 128 threads
    if (t < 8) scT[t] = expf(fminf(lsc[t], logf(100.0f)));
    if (t < 127) {
        float delta = (float)(t - 63);
        float sg = (delta > 0.f) ? 1.f : ((delta < 0.f) ? -1.f : 0.f);
        float r = sg * log1pf(fabsf(delta));
        float acc[8];
        #pragma unroll
        for (int q = 0; q < 8; ++q) acc[q] = b2[q];
        for (int m = 0; m < 384; ++m) {
            float hid = fmaxf(fmaf(r, w1[m * 2 + 1], b1[m]), 0.f);
            #pragma unroll
            for (int q = 0; q < 8; ++q) acc[q] = fmaf(hid, w2[q * 384 + m], acc[q]);
        }
        #pragma unroll
        for (int q = 0; q < 8; ++q) biasT[q * 127 + t] = acc[q];
    }
}

// ---------------- main fused kernel ----------------
// 256 threads (4 waves). Wave w owns rows w*16..w*16+15 through the WHOLE
// pipeline. x A-frags in registers (32 VGPR). Padded KL fragment layout in
// LDS (scatter-writes and b128 reads conflict-free). Q-norms in registers,
// K-norms via 512 B LDS — both PER HEAD (32 dims; R7 bug was 64-dim mix).
// 2 barriers per g. LDS = 46848 B; __launch_bounds__(256,3) -> 3 blocks/CU.

__global__ void __launch_bounds__(256, 3)
fused_win_attn(const float* __restrict__ x,
               const float* __restrict__ qkv_b,
               const float* __restrict__ proj_b,
               const short* __restrict__ wqs,
               const short* __restrict__ wps,
               const float* __restrict__ biasT,
               const float* __restrict__ scT,
               float* __restrict__ out)
{
    __shared__ short SH[23040];   // QGF@0 KGF@4608 VTF@9216 AOF@13824 PW@18432 (8 frags each)
    __shared__ float NSQK[128];   // k row norms^2, [hh][row]

    const int tid = threadIdx.x;
    const int w  = tid >> 6;
    const int l  = tid & 63;
    const int lg = l >> 4;
    const int lc = l & 15;
    const int li4 = lg * 4;
    const int blk = blockIdx.x;
    const int klb = KL(l) * 8;             // read offset inside a frag (shorts)

    short* QGF = SH;
    short* KGF = SH + 4608;
    short* VTF = SH + 9216;
    short* AOF = SH + 13824;
    short* PW  = SH + 18432 + w * (2 * FRS);   // wave-private, 2 frags

    // ---- x rows w*16+lc -> 8 register A-frags ----
    short8 xf[8];
    {
        const float* xr = x + (size_t)blk * (LTOK * CDIM) + (size_t)(w * 16 + lc) * CDIM + lg * 8;
        #pragma unroll
        for (int kt = 0; kt < 8; ++kt) {
            f32x4 a = *(const f32x4*)(xr + kt * 32);
            f32x4 b = *(const f32x4*)(xr + kt * 32 + 4);
            short8 t;
            t[0]=f2bf(a[0]); t[1]=f2bf(a[1]); t[2]=f2bf(a[2]); t[3]=f2bf(a[3]);
            t[4]=f2bf(b[0]); t[5]=f2bf(b[1]); t[6]=f2bf(b[2]); t[7]=f2bf(b[3]);
            xf[kt] = t;
        }
    }

    f32x4 accP[4][4];                      // proj accumulators (wave cols 64w..)
    #pragma unroll
    for (int a = 0; a < 4; ++a)
        #pragma unroll
        for (int b = 0; b < 4; ++b) accP[a][b] = (f32x4){0,0,0,0};
    const f32x4 fzero = {0.f, 0.f, 0.f, 0.f};

    #pragma unroll 1
    for (int g = 0; g < 4; ++g) {
        // ======== qkv: mt=w, strips 0..11 in pairs ========
        float rnq[2][4], rnk[2][4];        // PER-HEAD sumsq (R7 bug: mixed heads)
        #pragma unroll
        for (int hh = 0; hh < 2; ++hh)
            #pragma unroll
            for (int i = 0; i < 4; ++i) { rnq[hh][i] = 1e-24f; rnk[hh][i] = 1e-24f; }

        #pragma unroll
        for (int sg = 0; sg < 6; ++sg) {
            const int st0 = sg * 2, st1 = sg * 2 + 1;
            const int gnt0 = (st0 >> 2) * 16 + g * 4 + (st0 & 3);
            const int gnt1 = (st1 >> 2) * 16 + g * 4 + (st1 & 3);
            const short* wb0 = wqs + ((size_t)(gnt0 * 8) * 64 + l) * 8;
            const short* wb1 = wqs + ((size_t)(gnt1 * 8) * 64 + l) * 8;
            f32x4 a0 = fzero, a1 = fzero;
            #pragma unroll
            for (int kt = 0; kt < 8; ++kt) {
                short8 Bf0 = *(const short8*)(wb0 + kt * 512);
                short8 Bf1 = *(const short8*)(wb1 + kt * 512);
                a0 = __builtin_amdgcn_mfma_f32_16x16x32_bf16(xf[kt], Bf0, a0, 0, 0, 0);
                a1 = __builtin_amdgcn_mfma_f32_16x16x32_bf16(xf[kt], Bf1, a1, 0, 0, 0);
            }
            // epilogues (s, nt compile-time under unroll)
            #pragma unroll
            for (int e = 0; e < 2; ++e) {
                const int strip = e ? st1 : st0;
                const f32x4 av = e ? a1 : a0;
                const int s = strip >> 2, nt = strip & 3;
                const float bq = qkv_b[s * 256 + g * 64 + nt * 16 + lc];
                if (s < 2) {
                    short* base = (s ? KGF : QGF) + ((nt >> 1) * 4 + w) * FRS;
                    const int lgc = (nt & 1) * 2 + (lc >> 3);
                    #pragma unroll
                    for (int i = 0; i < 4; ++i) {
                        float v = av[i] + bq;
                        if (s == 0) rnq[nt >> 1][i] = fmaf(v, v, rnq[nt >> 1][i]);
                        else        rnk[nt >> 1][i] = fmaf(v, v, rnk[nt >> 1][i]);
                        const int l2 = lgc * 16 + li4 + i;
                        base[KL(l2) * 8 + (lc & 7)] = f2bf(v);
                    }
                } else {
                    // V transpose-store: one b64 per lane (4 consecutive shorts)
                    short* base = VTF + ((w >> 1) * 4 + nt) * FRS;
                    const int l2 = ((w & 1) * 2 + (lg >> 1)) * 16 + lc;
                    short4_t pk;
                    #pragma unroll
                    for (int i = 0; i < 4; ++i) pk[i] = f2bf(av[i] + bq);
                    *(short4_t*)(base + KL(l2) * 8 + (li4 & 7)) = pk;
                }
            }
        }
        // ---- norm reduce (rows stay lane-aligned for attn); per head ----
        float invqb[2][4];
        #pragma unroll
        for (int hh = 0; hh < 2; ++hh)
            #pragma unroll
            for (int i = 0; i < 4; ++i) {
                float t = rnq[hh][i];
                t += __shfl_xor(t, 1); t += __shfl_xor(t, 2);
                t += __shfl_xor(t, 4); t += __shfl_xor(t, 8);
                invqb[hh][i] = rsqrtf(t);
                float u = rnk[hh][i];
                u += __shfl_xor(u, 1); u += __shfl_xor(u, 2);
                u += __shfl_xor(u, 4); u += __shfl_xor(u, 8);
                if (lc == 0) NSQK[hh * 64 + w * 16 + li4 + i] = u;
            }
        __syncthreads();                   // B1: QGF/KGF/VTF/NSQK ready

        // ======== attention: wave = rows w*16..+15, both heads sequential ========
        #pragma unroll 1
        for (int hh = 0; hh < 2; ++hh) {
            const int h = 2 * g + hh;
            const float sc = scT[h];
            short8 Aq = *(const short8*)(QGF + (hh * 4 + w) * FRS + klb);
            f32x4 pacc[4];
            #pragma unroll
            for (int nt = 0; nt < 4; ++nt) {
                short8 Bk = *(const short8*)(KGF + (hh * 4 + nt) * FRS + klb);
                pacc[nt] = __builtin_amdgcn_mfma_f32_16x16x32_bf16(Aq, Bk, fzero, 0, 0, 0);
            }
            float invk[4];
            #pragma unroll
            for (int nt = 0; nt < 4; ++nt) invk[nt] = rsqrtf(NSQK[hh * 64 + nt * 16 + lc]);
            const float* bt = biasT + h * 127 + w * 16 + 63 - lc;
            float p[4][4];
            #pragma unroll
            for (int i = 0; i < 4; ++i) {
                const float iq = invqb[hh][i] * sc;
                #pragma unroll
                for (int nt = 0; nt < 4; ++nt)
                    p[i][nt] = pacc[nt][i] * iq * invk[nt] + bt[li4 + i - nt * 16];
            }
            // softmax per row
            #pragma unroll
            for (int i = 0; i < 4; ++i) {
                float m = fmaxf(fmaxf(p[i][0], p[i][1]), fmaxf(p[i][2], p[i][3]));
                m = fmaxf(m, __shfl_xor(m, 1));
                m = fmaxf(m, __shfl_xor(m, 2));
                m = fmaxf(m, __shfl_xor(m, 4));
                m = fmaxf(m, __shfl_xor(m, 8));
                float ssum = 0.f;
                #pragma unroll
                for (int nt = 0; nt < 4; ++nt) { p[i][nt] = __expf(p[i][nt] - m); ssum += p[i][nt]; }
                ssum += __shfl_xor(ssum, 1);
                ssum += __shfl_xor(ssum, 2);
                ssum += __shfl_xor(ssum, 4);
                ssum += __shfl_xor(ssum, 8);
                const float rinv = 1.f / ssum;
                #pragma unroll
                for (int nt = 0; nt < 4; ++nt) p[i][nt] *= rinv;
            }
            // P -> wave-private padded frags (A-layout)
            #pragma unroll
            for (int i = 0; i < 4; ++i)
                #pragma unroll
                for (int nt = 0; nt < 4; ++nt) {
                    const int l2 = ((nt & 1) * 2 + (lc >> 3)) * 16 + li4 + i;
                    PW[(nt >> 1) * FRS + KL(l2) * 8 + (lc & 7)] = f2bf(p[i][nt]);
                }
            // P @ V
            f32x4 oacc[2];
            oacc[0] = fzero; oacc[1] = fzero;
            #pragma unroll
            for (int ktp = 0; ktp < 2; ++ktp) {
                short8 Ap = *(const short8*)(PW + ktp * FRS + klb);
                #pragma unroll
                for (int ndv = 0; ndv < 2; ++ndv) {
                    short8 Bv = *(const short8*)(VTF + (ktp * 4 + hh * 2 + ndv) * FRS + klb);
                    oacc[ndv] = __builtin_amdgcn_mfma_f32_16x16x32_bf16(Ap, Bv, oacc[ndv], 0, 0, 0);
                }
            }
            // AO -> padded frag (proj A-layout), slot (hh, mt=w)
            #pragma unroll
            for (int ndv = 0; ndv < 2; ++ndv)
                #pragma unroll
                for (int i = 0; i < 4; ++i) {
                    const int l2 = (ndv * 2 + (lc >> 3)) * 16 + li4 + i;
                    AOF[(hh * 4 + w) * FRS + KL(l2) * 8 + (lc & 7)] = f2bf(oacc[ndv][i]);
                }
        }
        __syncthreads();                   // B2: AOF ready

        // ======== proj accumulate: wave w owns cols 64w..64w+63 ========
        #pragma unroll
        for (int hh2 = 0; hh2 < 2; ++hh2) {
            const int h2 = 2 * g + hh2;
            short8 Aa0 = *(const short8*)(AOF + (hh2 * 4 + 0) * FRS + klb);
            short8 Aa1 = *(const short8*)(AOF + (hh2 * 4 + 1) * FRS + klb);
            short8 Aa2 = *(const short8*)(AOF + (hh2 * 4 + 2) * FRS + klb);
            short8 Aa3 = *(const short8*)(AOF + (hh2 * 4 + 3) * FRS + klb);
            #pragma unroll
            for (int ntl = 0; ntl < 4; ++ntl) {
                short8 Bp = *(const short8*)(wps + ((size_t)((w * 4 + ntl) * 8 + h2) * 64 + l) * 8);
                accP[0][ntl] = __builtin_amdgcn_mfma_f32_16x16x32_bf16(Aa0, Bp, accP[0][ntl], 0, 0, 0);
                accP[1][ntl] = __builtin_amdgcn_mfma_f32_16x16x32_bf16(Aa1, Bp, accP[1][ntl], 0, 0, 0);
                accP[2][ntl] = __builtin_amdgcn_mfma_f32_16x16x32_bf16(Aa2, Bp, accP[2][ntl], 0, 0, 0);
                accP[3][ntl] = __builtin_amdgcn_mfma_f32_16x16x32_bf16(Aa3, Bp, accP[3][ntl], 0, 0, 0);
            }
        }
        // no barrier: attn(g+1) writes to AOF occur only after B1(g+1)
    }

    // ---- epilogue: out = accP + proj_b ----
    {
        float* ob = out + (size_t)blk * (LTOK * CDIM);
        #pragma unroll
        for (int ntl = 0; ntl < 4; ++ntl) {
            const float pb = proj_b[w * 64 + ntl * 16 + lc];
            #pragma unroll
            for (int mt = 0; mt < 4; ++mt)
                #pragma unroll
                for (int i = 0; i < 4; ++i)
                    ob[(size_t)(mt * 16 + li4 + i) * 256 + w * 64 + ntl * 16 + lc] = accP[mt][ntl][i] + pb;
        }
    }
}

extern "C" void kernel_launch(void* const* d_in, const int* in_sizes, int n_in,
                              void* d_out, int out_size, void* d_ws, size_t ws_size,
                              hipStream_t stream) {
    const float* x     = (const float*)d_in[0];
    const float* qkvw  = (const float*)d_in[1];
    const float* qkvb  = (const float*)d_in[2];
    const float* projw = (const float*)d_in[3];
    const float* projb = (const float*)d_in[4];
    const float* lsc   = (const float*)d_in[5];
    const float* w1    = (const float*)d_in[6];
    const float* b1    = (const float*)d_in[7];
    const float* w2    = (const float*)d_in[8];
    const float* b2    = (const float*)d_in[9];
    float* out = (float*)d_out;

    // workspace layout
    short* wqs   = (short*)d_ws;                          // 393216 B
    short* wps   = (short*)((char*)d_ws + 393216);        // 131072 B
    float* biasT = (float*)((char*)d_ws + 524288);        // 4096 B
    float* scT   = (float*)((char*)d_ws + 528384);        // 32 B

    const int nwin = in_sizes[0] / (LTOK * CDIM);         // 4096

    prep_weights<<<768, 256, 0, stream>>>(qkvw, projw, wqs, wps);
    prep_bias<<<1, 128, 0, stream>>>(w1, b1, w2, b2, lsc, biasT, scT);
    fused_win_attn<<<nwin, 256, 0, stream>>>(x, qkvb, projb, wqs, wps, biasT, scT, out);
}

// Round 9
// 546.755 us; speedup vs baseline: 1.8259x; 1.3471x over previous
//
#include <hip/hip_runtime.h>
#include <hip/hip_bf16.h>

typedef __attribute__((ext_vector_type(4))) float f32x4;
typedef __attribute__((ext_vector_type(8))) short short8;
typedef __attribute__((ext_vector_type(4))) short short4_t;

#define LTOK 64
#define CDIM 256
#define FRS 576            // padded frag stride (shorts): 72 blocks x 8

static __device__ __forceinline__ short f2bf(float f) {
    __hip_bfloat16 h = __float2bfloat16(f);
    union { __hip_bfloat16 b; short s; } u; u.b = h;
    return u.s;
}
static __device__ __forceinline__ int KL(int l) { return l + (l >> 3); }

// ---------------- prep kernels ----------------
__global__ void prep_weights(const float* __restrict__ qw, const float* __restrict__ pw,
                             short* __restrict__ wqs, short* __restrict__ wps) {
    int i = blockIdx.x * 256 + threadIdx.x;     // grid 768*256 = 196608
    if (i < 768 * 256) {
        int row = i >> 8, col = i & 255;
        int nt = row >> 4, lcr = row & 15;
        int kt = col >> 5, lg = (col >> 3) & 3, j = col & 7;
        wqs[(size_t)(((nt * 8 + kt) * 64) + lg * 16 + lcr) * 8 + j] = f2bf(qw[i]);
    }
    if (i < 256 * 256) {
        int row = i >> 8, col = i & 255;
        int gs = row >> 4, lcr = row & 15;          // global 16-col strip 0..15
        int h = col >> 5, lg = (col >> 3) & 3, j = col & 7;
        wps[(size_t)(((gs * 8 + h) * 64) + lg * 16 + lcr) * 8 + j] = f2bf(pw[i]);
    }
}

__global__ void prep_bias(const float* __restrict__ w1, const float* __restrict__ b1,
                          const float* __restrict__ w2, const float* __restrict__ b2,
                          const float* __restrict__ lsc, float* __restrict__ biasT,
                          float* __restrict__ scT) {
    int t = threadIdx.x;                         // 1 block, 128 threads
    if (t < 8) scT[t] = expf(fminf(lsc[t], logf(100.0f)));
    if (t < 127) {
        float delta = (float)(t - 63);
        float sg = (delta > 0.f) ? 1.f : ((delta < 0.f) ? -1.f : 0.f);
        float r = sg * log1pf(fabsf(delta));
        float acc[8];
        #pragma unroll
        for (int q = 0; q < 8; ++q) acc[q] = b2[q];
        for (int m = 0; m < 384; ++m) {
            float hid = fmaxf(fmaf(r, w1[m * 2 + 1], b1[m]), 0.f);
            #pragma unroll
            for (int q = 0; q < 8; ++q) acc[q] = fmaf(hid, w2[q * 384 + m], acc[q]);
        }
        #pragma unroll
        for (int q = 0; q < 8; ++q) biasT[q * 127 + t] = acc[q];
    }
}

// ---------------- kernel A: qkv + attention ----------------
// 256 threads (4 waves), one block per window. Wave w owns rows w*16..+15.
// x A-frags in registers (32 VGPR); NO proj accumulators (proj moved to
// kernel B) -> fits (256,4): 4 blocks/CU, 16 waves/CU.
// AO (64x256 bf16) written to the SECOND HALF of this window's d_out region
// (floats [8192,16384)) — consumed by proj_win, which overwrites all of out.
// 2 barriers per g. LDS = 37376 B (4 x 37376 = 149.5 KB/CU).

__global__ void __launch_bounds__(256, 4)
fused_win_attn(const float* __restrict__ x,
               const float* __restrict__ qkv_b,
               const short* __restrict__ wqs,
               const float* __restrict__ biasT,
               const float* __restrict__ scT,
               float* out)
{
    __shared__ short SH[18432];   // QGF@0 KGF@4608 VTF@9216 PW@13824 (8 frags each)
    __shared__ float NSQK[128];   // k row norms^2, [hh][row]

    const int tid = threadIdx.x;
    const int w  = tid >> 6;
    const int l  = tid & 63;
    const int lg = l >> 4;
    const int lc = l & 15;
    const int li4 = lg * 4;
    const int blk = blockIdx.x;
    const int klb = KL(l) * 8;             // read offset inside a frag (shorts)

    short* QGF = SH;
    short* KGF = SH + 4608;
    short* VTF = SH + 9216;
    short* PW  = SH + 13824 + w * (2 * FRS);   // wave-private, 2 frags

    short* ao = (short*)(out + (size_t)blk * (LTOK * CDIM) + 8192);  // bf16 AO scratch

    // ---- x rows w*16+lc -> 8 register A-frags ----
    short8 xf[8];
    {
        const float* xr = x + (size_t)blk * (LTOK * CDIM) + (size_t)(w * 16 + lc) * CDIM + lg * 8;
        #pragma unroll
        for (int kt = 0; kt < 8; ++kt) {
            f32x4 a = *(const f32x4*)(xr + kt * 32);
            f32x4 b = *(const f32x4*)(xr + kt * 32 + 4);
            short8 t;
            t[0]=f2bf(a[0]); t[1]=f2bf(a[1]); t[2]=f2bf(a[2]); t[3]=f2bf(a[3]);
            t[4]=f2bf(b[0]); t[5]=f2bf(b[1]); t[6]=f2bf(b[2]); t[7]=f2bf(b[3]);
            xf[kt] = t;
        }
    }
    const f32x4 fzero = {0.f, 0.f, 0.f, 0.f};

    #pragma unroll 1
    for (int g = 0; g < 4; ++g) {
        // ======== qkv: mt=w, strips 0..11 in pairs ========
        float rnq[2][4], rnk[2][4];        // PER-HEAD sumsq
        #pragma unroll
        for (int hh = 0; hh < 2; ++hh)
            #pragma unroll
            for (int i = 0; i < 4; ++i) { rnq[hh][i] = 1e-24f; rnk[hh][i] = 1e-24f; }

        #pragma unroll
        for (int sg = 0; sg < 6; ++sg) {
            const int st0 = sg * 2, st1 = sg * 2 + 1;
            const int gnt0 = (st0 >> 2) * 16 + g * 4 + (st0 & 3);
            const int gnt1 = (st1 >> 2) * 16 + g * 4 + (st1 & 3);
            const short* wb0 = wqs + ((size_t)(gnt0 * 8) * 64 + l) * 8;
            const short* wb1 = wqs + ((size_t)(gnt1 * 8) * 64 + l) * 8;
            f32x4 a0 = fzero, a1 = fzero;
            #pragma unroll
            for (int kt = 0; kt < 8; ++kt) {
                short8 Bf0 = *(const short8*)(wb0 + kt * 512);
                short8 Bf1 = *(const short8*)(wb1 + kt * 512);
                a0 = __builtin_amdgcn_mfma_f32_16x16x32_bf16(xf[kt], Bf0, a0, 0, 0, 0);
                a1 = __builtin_amdgcn_mfma_f32_16x16x32_bf16(xf[kt], Bf1, a1, 0, 0, 0);
            }
            #pragma unroll
            for (int e = 0; e < 2; ++e) {
                const int strip = e ? st1 : st0;
                const f32x4 av = e ? a1 : a0;
                const int s = strip >> 2, nt = strip & 3;
                const float bq = qkv_b[s * 256 + g * 64 + nt * 16 + lc];
                if (s < 2) {
                    short* base = (s ? KGF : QGF) + ((nt >> 1) * 4 + w) * FRS;
                    const int lgc = (nt & 1) * 2 + (lc >> 3);
                    #pragma unroll
                    for (int i = 0; i < 4; ++i) {
                        float v = av[i] + bq;
                        if (s == 0) rnq[nt >> 1][i] = fmaf(v, v, rnq[nt >> 1][i]);
                        else        rnk[nt >> 1][i] = fmaf(v, v, rnk[nt >> 1][i]);
                        const int l2 = lgc * 16 + li4 + i;
                        base[KL(l2) * 8 + (lc & 7)] = f2bf(v);
                    }
                } else {
                    short* base = VTF + ((w >> 1) * 4 + nt) * FRS;
                    const int l2 = ((w & 1) * 2 + (lg >> 1)) * 16 + lc;
                    short4_t pk;
                    #pragma unroll
                    for (int i = 0; i < 4; ++i) pk[i] = f2bf(av[i] + bq);
                    *(short4_t*)(base + KL(l2) * 8 + (li4 & 7)) = pk;
                }
            }
        }
        // ---- norm reduce; per head ----
        float invqb[2][4];
        #pragma unroll
        for (int hh = 0; hh < 2; ++hh)
            #pragma unroll
            for (int i = 0; i < 4; ++i) {
                float t = rnq[hh][i];
                t += __shfl_xor(t, 1); t += __shfl_xor(t, 2);
                t += __shfl_xor(t, 4); t += __shfl_xor(t, 8);
                invqb[hh][i] = rsqrtf(t);
                float u = rnk[hh][i];
                u += __shfl_xor(u, 1); u += __shfl_xor(u, 2);
                u += __shfl_xor(u, 4); u += __shfl_xor(u, 8);
                if (lc == 0) NSQK[hh * 64 + w * 16 + li4 + i] = u;
            }
        __syncthreads();                   // B1: QGF/KGF/VTF/NSQK ready

        // ======== attention: wave = rows w*16..+15, both heads sequential ========
        #pragma unroll 1
        for (int hh = 0; hh < 2; ++hh) {
            const int h = 2 * g + hh;
            const float sc = scT[h];
            short8 Aq = *(const short8*)(QGF + (hh * 4 + w) * FRS + klb);
            f32x4 pacc[4];
            #pragma unroll
            for (int nt = 0; nt < 4; ++nt) {
                short8 Bk = *(const short8*)(KGF + (hh * 4 + nt) * FRS + klb);
                pacc[nt] = __builtin_amdgcn_mfma_f32_16x16x32_bf16(Aq, Bk, fzero, 0, 0, 0);
            }
            float invk[4];
            #pragma unroll
            for (int nt = 0; nt < 4; ++nt) invk[nt] = rsqrtf(NSQK[hh * 64 + nt * 16 + lc]);
            const float* bt = biasT + h * 127 + w * 16 + 63 - lc;
            float p[4][4];
            #pragma unroll
            for (int i = 0; i < 4; ++i) {
                const float iq = invqb[hh][i] * sc;
                #pragma unroll
                for (int nt = 0; nt < 4; ++nt)
                    p[i][nt] = pacc[nt][i] * iq * invk[nt] + bt[li4 + i - nt * 16];
            }
            #pragma unroll
            for (int i = 0; i < 4; ++i) {
                float m = fmaxf(fmaxf(p[i][0], p[i][1]), fmaxf(p[i][2], p[i][3]));
                m = fmaxf(m, __shfl_xor(m, 1));
                m = fmaxf(m, __shfl_xor(m, 2));
                m = fmaxf(m, __shfl_xor(m, 4));
                m = fmaxf(m, __shfl_xor(m, 8));
                float ssum = 0.f;
                #pragma unroll
                for (int nt = 0; nt < 4; ++nt) { p[i][nt] = __expf(p[i][nt] - m); ssum += p[i][nt]; }
                ssum += __shfl_xor(ssum, 1);
                ssum += __shfl_xor(ssum, 2);
                ssum += __shfl_xor(ssum, 4);
                ssum += __shfl_xor(ssum, 8);
                const float rinv = 1.f / ssum;
                #pragma unroll
                for (int nt = 0; nt < 4; ++nt) p[i][nt] *= rinv;
            }
            // P -> wave-private padded frags (A-layout)
            #pragma unroll
            for (int i = 0; i < 4; ++i)
                #pragma unroll
                for (int nt = 0; nt < 4; ++nt) {
                    const int l2 = ((nt & 1) * 2 + (lc >> 3)) * 16 + li4 + i;
                    PW[(nt >> 1) * FRS + KL(l2) * 8 + (lc & 7)] = f2bf(p[i][nt]);
                }
            // P @ V
            f32x4 oacc[2];
            oacc[0] = fzero; oacc[1] = fzero;
            #pragma unroll
            for (int ktp = 0; ktp < 2; ++ktp) {
                short8 Ap = *(const short8*)(PW + ktp * FRS + klb);
                #pragma unroll
                for (int ndv = 0; ndv < 2; ++ndv) {
                    short8 Bv = *(const short8*)(VTF + (ktp * 4 + hh * 2 + ndv) * FRS + klb);
                    oacc[ndv] = __builtin_amdgcn_mfma_f32_16x16x32_bf16(Ap, Bv, oacc[ndv], 0, 0, 0);
                }
            }
            // AO -> global bf16 scratch, row-major [row][h*32+d]
            #pragma unroll
            for (int ndv = 0; ndv < 2; ++ndv)
                #pragma unroll
                for (int i = 0; i < 4; ++i)
                    ao[(w * 16 + li4 + i) * 256 + h * 32 + ndv * 16 + lc] = f2bf(oacc[ndv][i]);
        }
        __syncthreads();                   // B2: attn reads done before next-g LDS writes
    }
}

// ---------------- kernel B: proj GEMM per window ----------------
// 256 threads, one block per window. Stages AO (from out's second half) into
// padded LDS frags — ALL reads complete before ANY write to out (single
// barrier), so reusing d_out as AO scratch is race-free (window-private).
// Wave w computes output cols 64w..64w+63 for all 64 rows.

__global__ void __launch_bounds__(256, 4)
proj_win(const float* __restrict__ proj_b,
         const short* __restrict__ wps,
         float* out)
{
    __shared__ short AF[32 * FRS];    // 36864 B

    const int tid = threadIdx.x;
    const int w  = tid >> 6;
    const int l  = tid & 63;
    const int lg = l >> 4;
    const int lc = l & 15;
    const int li4 = lg * 4;
    const int blk = blockIdx.x;
    const int klb = KL(l) * 8;

    const short* ao = (const short*)(out + (size_t)blk * (LTOK * CDIM) + 8192);

    // ---- stage AO into fragment LDS (8 frags per wave, conflict-free) ----
    #pragma unroll
    for (int u = 0; u < 8; ++u) {
        const int f = w * 8 + u;
        const int kt = f >> 2, mt = f & 3;
        short8 t = *(const short8*)(ao + (mt * 16 + lc) * 256 + kt * 32 + lg * 8);
        *(short8*)(AF + f * FRS + klb) = t;
    }
    __syncthreads();

    f32x4 accP[4][4];
    #pragma unroll
    for (int a = 0; a < 4; ++a)
        #pragma unroll
        for (int b = 0; b < 4; ++b) accP[a][b] = (f32x4){0,0,0,0};

    #pragma unroll
    for (int kt = 0; kt < 8; ++kt) {
        short8 Aa0 = *(const short8*)(AF + (kt * 4 + 0) * FRS + klb);
        short8 Aa1 = *(const short8*)(AF + (kt * 4 + 1) * FRS + klb);
        short8 Aa2 = *(const short8*)(AF + (kt * 4 + 2) * FRS + klb);
        short8 Aa3 = *(const short8*)(AF + (kt * 4 + 3) * FRS + klb);
        #pragma unroll
        for (int ntl = 0; ntl < 4; ++ntl) {
            short8 Bp = *(const short8*)(wps + ((size_t)((w * 4 + ntl) * 8 + kt) * 64 + l) * 8);
            accP[0][ntl] = __builtin_amdgcn_mfma_f32_16x16x32_bf16(Aa0, Bp, accP[0][ntl], 0, 0, 0);
            accP[1][ntl] = __builtin_amdgcn_mfma_f32_16x16x32_bf16(Aa1, Bp, accP[1][ntl], 0, 0, 0);
            accP[2][ntl] = __builtin_amdgcn_mfma_f32_16x16x32_bf16(Aa2, Bp, accP[2][ntl], 0, 0, 0);
            accP[3][ntl] = __builtin_amdgcn_mfma_f32_16x16x32_bf16(Aa3, Bp, accP[3][ntl], 0, 0, 0);
        }
    }

    // ---- epilogue: out = accP + proj_b (overwrites AO region too) ----
    float* ob = out + (size_t)blk * (LTOK * CDIM);
    #pragma unroll
    for (int ntl = 0; ntl < 4; ++ntl) {
        const float pb = proj_b[w * 64 + ntl * 16 + lc];
        #pragma unroll
        for (int mt = 0; mt < 4; ++mt)
            #pragma unroll
            for (int i = 0; i < 4; ++i)
                ob[(size_t)(mt * 16 + li4 + i) * 256 + w * 64 + ntl * 16 + lc] = accP[mt][ntl][i] + pb;
    }
}

extern "C" void kernel_launch(void* const* d_in, const int* in_sizes, int n_in,
                              void* d_out, int out_size, void* d_ws, size_t ws_size,
                              hipStream_t stream) {
    const float* x     = (const float*)d_in[0];
    const float* qkvw  = (const float*)d_in[1];
    const float* qkvb  = (const float*)d_in[2];
    const float* projw = (const float*)d_in[3];
    const float* projb = (const float*)d_in[4];
    const float* lsc   = (const float*)d_in[5];
    const float* w1    = (const float*)d_in[6];
    const float* b1    = (const float*)d_in[7];
    const float* w2    = (const float*)d_in[8];
    const float* b2    = (const float*)d_in[9];
    float* out = (float*)d_out;

    // workspace layout
    short* wqs   = (short*)d_ws;                          // 393216 B
    short* wps   = (short*)((char*)d_ws + 393216);        // 131072 B
    float* biasT = (float*)((char*)d_ws + 524288);        // 4096 B
    float* scT   = (float*)((char*)d_ws + 528384);        // 32 B

    const int nwin = in_sizes[0] / (LTOK * CDIM);         // 4096

    prep_weights<<<768, 256, 0, stream>>>(qkvw, projw, wqs, wps);
    prep_bias<<<1, 128, 0, stream>>>(w1, b1, w2, b2, lsc, biasT, scT);
    fused_win_attn<<<nwin, 256, 0, stream>>>(x, qkvb, wqs, biasT, scT, out);
    proj_win<<<nwin, 256, 0, stream>>>(projb, wps, out);
}